// Round 9
// baseline (4098.915 us; speedup 1.0000x reference)
//
#include <hip/hip_runtime.h>

#define NB 16          // batches
#define NPTS 131072    // points per batch
#define NPOINT 1024
#define HID 192
#define OUTC 384
#define THREADS_FPS 1024
#define PTS_PER_T 8
#define TAG_INIT 1023u   // tags run 0..1022, never 1023
#define TAGM 0x3FFu

static __device__ __forceinline__ unsigned long long ald_ag(const unsigned long long* p) {
  return __hip_atomic_load(p, __ATOMIC_RELAXED, __HIP_MEMORY_SCOPE_AGENT);
}
static __device__ __forceinline__ void ast_ag(unsigned long long* p, unsigned long long v) {
  __hip_atomic_store(p, v, __ATOMIC_RELAXED, __HIP_MEMORY_SCOPE_AGENT);
}
__device__ __forceinline__ unsigned long long shflxor_max_u64(unsigned long long v, int off) {
  unsigned int lo = (unsigned int)v, hi = (unsigned int)(v >> 32);
  lo = __shfl_xor(lo, off, 64);
  hi = __shfl_xor(hi, off, 64);
  unsigned long long o = ((unsigned long long)hi << 32) | lo;
  return o > v ? o : v;
}

// LDS-only barrier: drain lgkmcnt, raw s_barrier. Prefetched global (vmcnt)
// loads stay in flight across it — __syncthreads would drain vmcnt(0) and
// re-expose the fabric RT we are hiding. (m139/HipKittens pattern.)
__device__ __forceinline__ void bar_lds() {
  asm volatile("s_waitcnt lgkmcnt(0)" ::: "memory");
  __builtin_amdgcn_s_barrier();
}

// md update + per-thread argmax + wave reduce; returns block-wave key (lane 0).
__device__ __forceinline__ unsigned long long wave_key(
    float (&px)[PTS_PER_T], float (&py)[PTS_PER_T], float (&pz)[PTS_PER_T],
    float (&md)[PTS_PER_T], float lx, float ly, float lz, int base, int t)
{
  float bm = -1.0f; int bk = 0;
#pragma unroll
  for (int k = 0; k < PTS_PER_T; ++k) {
    float dx = px[k] - lx, dy = py[k] - ly, dz = pz[k] - lz;
    // numpy op order, no FMA contraction: (dx*dx + dy*dy) + dz*dz
    float d = __fadd_rn(__fadd_rn(__fmul_rn(dx, dx), __fmul_rn(dy, dy)), __fmul_rn(dz, dz));
    float m = fminf(md[k], d);
    md[k] = m;
    if (m > bm) { bm = m; bk = k; }   // strict >: smallest k == smallest idx
  }
  int bi = base + (bk << 10) + t;
  unsigned long long key = ((unsigned long long)__float_as_uint(bm) << 32)
                         | ((unsigned long long)(unsigned)(NPTS - 1 - bi) << 15);
#pragma unroll
  for (int off = 32; off > 0; off >>= 1) {
    unsigned int lo = (unsigned int)key, hi = (unsigned int)(key >> 32);
    lo = __shfl_down(lo, off, 64);
    hi = __shfl_down(hi, off, 64);
    unsigned long long o = ((unsigned long long)hi << 32) | lo;
    key = o > key ? o : key;
  }
  return key;
}

// Check two prefetched probes; fall back to a fresh 2-deep retry loop.
__device__ __forceinline__ unsigned long long check2(
    unsigned long long q0, unsigned long long q1,
    const unsigned long long* pw, unsigned int uit)
{
  if (((unsigned int)q0 & TAGM) == uit) return q0;
  if (((unsigned int)q1 & TAGM) == uit) return q1;
  for (;;) {
    unsigned long long a0 = ald_ag(pw);
    unsigned long long a1 = ald_ag(pw);
    if (((unsigned int)a0 & TAGM) == uit) return a0;
    if (((unsigned int)a1 & TAGM) == uit) return a1;
  }
}

// 4-step xor max over lanes 0..15 (all hold same result) -> winner index.
__device__ __forceinline__ int global_gi(unsigned long long pv) {
  pv = shflxor_max_u64(pv, 8);
  pv = shflxor_max_u64(pv, 4);
  pv = shflxor_max_u64(pv, 2);
  pv = shflxor_max_u64(pv, 1);
  return NPTS - 1 - (int)((pv >> 15) & 0x1FFFFull);
}

// ---------------- FPS: two phase-shifted chains per block ----------------
// 128 blocks. Block j: chain A = (batch j>>4, slice j&15), chain B =
// (batch 8+(j>>4), slice j&15). Per chain, the round-8 protocol: one 128B
// line per (batch,parity) of 16 tagged keys; publish by lane0; poll lanes
// 0..15. The two chains are interleaved half-an-iteration out of phase so
// each chain's publish->detect round-trip is hidden under the other chain's
// update compute; probe loads are prefetched an entire segment early and
// kept in flight across raw barriers.
__global__ __launch_bounds__(1024) void fps_kernel(
    const float* __restrict__ points,
    unsigned long long* __restrict__ slots,   // [NB][2][16]
    int* __restrict__ fps_idx)                // [NB][NPOINT], [b][0]=0 pre-set
{
  const int j = blockIdx.x;        // 0..127
  const int bA = j >> 4;           // 0..7
  const int bB = bA + 8;           // 8..15
  const int r  = j & 15;
  const int t = threadIdx.x;
  const int lane = t & 63, wid = t >> 6;
  const float* __restrict__ PA = points + (size_t)bA * NPTS * 3;
  const float* __restrict__ PB = points + (size_t)bB * NPTS * 3;
  const int base = r << 13;        // r * 8192

  float pxA[PTS_PER_T], pyA[PTS_PER_T], pzA[PTS_PER_T], mdA[PTS_PER_T];
  float pxB[PTS_PER_T], pyB[PTS_PER_T], pzB[PTS_PER_T], mdB[PTS_PER_T];
#pragma unroll
  for (int k = 0; k < PTS_PER_T; ++k) {
    int i = base + (k << 10) + t;
    const float* pa = PA + (size_t)i * 3;
    const float* pb = PB + (size_t)i * 3;
    pxA[k] = pa[0]; pyA[k] = pa[1]; pzA[k] = pa[2]; mdA[k] = 1e10f;
    pxB[k] = pb[0]; pyB[k] = pb[1]; pzB[k] = pb[2]; mdB[k] = 1e10f;
  }

  __shared__ unsigned long long s_redA[16], s_redB[16];
  __shared__ float s_wA[3], s_wB[3];

  unsigned long long* regionA = slots + (size_t)bA * 32;  // [2][16]
  unsigned long long* regionB = slots + (size_t)bB * 32;

  // ---- prologue: iteration 0 (last = point 0) ----
  {
    unsigned long long kA = wave_key(pxA, pyA, pzA, mdA, PA[0], PA[1], PA[2], base, t);
    unsigned long long kB = wave_key(pxB, pyB, pzB, mdB, PB[0], PB[1], PB[2], base, t);
    if (lane == 0) { s_redA[wid] = kA; s_redB[wid] = kB; }
  }
  __syncthreads();

  unsigned long long qa0 = 0, qa1 = 0;   // prefetched A probes (loop-carried)
  if (wid == 0 && lane < 16) {
    unsigned long long kkA = s_redA[lane];
    kkA = shflxor_max_u64(kkA, 8); kkA = shflxor_max_u64(kkA, 4);
    kkA = shflxor_max_u64(kkA, 2); kkA = shflxor_max_u64(kkA, 1);
    unsigned long long kkB = s_redB[lane];
    kkB = shflxor_max_u64(kkB, 8); kkB = shflxor_max_u64(kkB, 4);
    kkB = shflxor_max_u64(kkB, 2); kkB = shflxor_max_u64(kkB, 1);
    if (lane == 0) {
      ast_ag(&regionA[r], kkA);          // parity 0, tag 0
      ast_ag(&regionB[r], kkB);
    }
    const unsigned long long* pwA = regionA + lane;
    qa0 = ald_ag(pwA); qa1 = ald_ag(pwA);
  }

  // ---- pipelined main loop: detect it, publish it+1 (it = 0..1021) ----
  for (int it = 0; it < NPOINT - 2; ++it) {
    const int par = it & 1;
    const int parn = par ^ 1;
    const unsigned int uit = (unsigned int)it;
    const unsigned long long tgn = (unsigned long long)(unsigned)(it + 1);
    unsigned long long qb0 = 0, qb1 = 0;

    // SEG0 (wave0): fire B(it) probes; detect A(it); winner coords -> s_wA
    if (wid == 0 && lane < 16) {
      const unsigned long long* pwB = regionB + (size_t)par * 16 + lane;
      qb0 = ald_ag(pwB); qb1 = ald_ag(pwB);
      unsigned long long pv = check2(qa0, qa1, regionA + (size_t)par * 16 + lane, uit);
      int gA = global_gi(pv);
      if (lane < 3) s_wA[lane] = PA[(size_t)3 * gA + lane];
      if (lane == 0 && r == 0) fps_idx[bA * NPOINT + it + 1] = gA;
    }
    bar_lds();

    // SEG1 (all): update chain A for it+1
    {
      float lx = s_wA[0], ly = s_wA[1], lz = s_wA[2];
      unsigned long long kA = wave_key(pxA, pyA, pzA, mdA, lx, ly, lz, base, t);
      if (lane == 0) s_redA[wid] = kA;
    }
    bar_lds();

    // SEG2 (wave0): reduce+publish A(it+1); detect B(it); coords -> s_wB
    if (wid == 0 && lane < 16) {
      unsigned long long kk = s_redA[lane];
      kk = shflxor_max_u64(kk, 8); kk = shflxor_max_u64(kk, 4);
      kk = shflxor_max_u64(kk, 2); kk = shflxor_max_u64(kk, 1);
      if (lane == 0) ast_ag(&regionA[(size_t)parn * 16 + r], kk | tgn);
      unsigned long long pv = check2(qb0, qb1, regionB + (size_t)par * 16 + lane, uit);
      int gB = global_gi(pv);
      if (lane < 3) s_wB[lane] = PB[(size_t)3 * gB + lane];
      if (lane == 0 && r == 0) fps_idx[bB * NPOINT + it + 1] = gB;
    }
    bar_lds();

    // SEG3 (all): update chain B for it+1
    {
      float lx = s_wB[0], ly = s_wB[1], lz = s_wB[2];
      unsigned long long kB = wave_key(pxB, pyB, pzB, mdB, lx, ly, lz, base, t);
      if (lane == 0) s_redB[wid] = kB;
    }
    bar_lds();

    // SEG4 (wave0): reduce+publish B(it+1); prefetch A(it+1) probes
    if (wid == 0 && lane < 16) {
      unsigned long long kk = s_redB[lane];
      kk = shflxor_max_u64(kk, 8); kk = shflxor_max_u64(kk, 4);
      kk = shflxor_max_u64(kk, 2); kk = shflxor_max_u64(kk, 1);
      if (lane == 0) ast_ag(&regionB[(size_t)parn * 16 + r], kk | tgn);
      const unsigned long long* pwA = regionA + (size_t)parn * 16 + lane;
      qa0 = ald_ag(pwA); qa1 = ald_ag(pwA);
    }
  }

  // ---- epilogue: detect iteration 1022 for both chains ----
  if (wid == 0 && lane < 16) {
    const int par = (NPOINT - 2) & 1;          // = 0
    const unsigned int uit = (unsigned int)(NPOINT - 2);
    unsigned long long pv = check2(qa0, qa1, regionA + (size_t)par * 16 + lane, uit);
    int gA = global_gi(pv);
    if (lane == 0 && r == 0) fps_idx[bA * NPOINT + NPOINT - 1] = gA;
    const unsigned long long* pwB = regionB + (size_t)par * 16 + lane;
    unsigned long long pv2;
    for (;;) {
      unsigned long long a0 = ald_ag(pwB);
      unsigned long long a1 = ald_ag(pwB);
      if (((unsigned int)a0 & TAGM) == uit) { pv2 = a0; break; }
      if (((unsigned int)a1 & TAGM) == uit) { pv2 = a1; break; }
    }
    int gB = global_gi(pv2);
    if (lane == 0 && r == 0) fps_idx[bB * NPOINT + NPOINT - 1] = gB;
  }
}

// ---------------- init ----------------
__global__ void fps_init_kernel(unsigned long long* __restrict__ slots,
                                int* __restrict__ fps_idx)
{
  int i = blockIdx.x * blockDim.x + threadIdx.x;
  if (i < NB * 2 * 16) slots[i] = (unsigned long long)TAG_INIT;
  if (i < NB) fps_idx[i * NPOINT] = 0;
}

// ---------------- MLP ----------------
// 4 rows (centers) per block, 384 threads. Phase 1: hidden (2 MLPs x 192)
// with exact GELU into LDS. Phase 2: thread o accumulates output column o.
__global__ __launch_bounds__(384) void mlp_kernel(
    const float* __restrict__ points,
    const int* __restrict__ fps_idx,
    const float* __restrict__ w1t, const float* __restrict__ b1t,
    const float* __restrict__ w2t, const float* __restrict__ b2t,
    const float* __restrict__ w1p, const float* __restrict__ b1p,
    const float* __restrict__ w2p, const float* __restrict__ b2p,
    float* __restrict__ out)
{
  __shared__ float s_c[4][3];
  __shared__ float s_h[2][HID][4];
  const int t = threadIdx.x;
  const int m0 = blockIdx.x * 4;
  if (t < 4) {
    int m = m0 + t;
    int b = m >> 10;
    int idx = fps_idx[m];
    const float* p = points + ((size_t)b * NPTS + (size_t)idx) * 3;
    s_c[t][0] = p[0]; s_c[t][1] = p[1]; s_c[t][2] = p[2];
  }
  __syncthreads();
  {
    const int mlp = t / HID;            // 0 = token, 1 = pos
    const int k = t - mlp * HID;
    const float* w1 = mlp ? w1p : w1t;
    const float* b1 = mlp ? b1p : b1t;
    float wa = w1[k], wb = w1[HID + k], wc = w1[2 * HID + k], bb = b1[k];
#pragma unroll
    for (int r = 0; r < 4; ++r) {
      float z = s_c[r][0] * wa + s_c[r][1] * wb + s_c[r][2] * wc + bb;
      float g = 0.5f * z * (1.0f + erff(z * 0.70710678118654752440f));
      s_h[mlp][k][r] = g;
    }
  }
  __syncthreads();
  const int o = t;
  float acct[4] = {0.f, 0.f, 0.f, 0.f};
  float accp[4] = {0.f, 0.f, 0.f, 0.f};
  const float* w2t_o = w2t + o;
  const float* w2p_o = w2p + o;
#pragma unroll 4
  for (int k = 0; k < HID; ++k) {
    float wt = w2t_o[(size_t)k * OUTC];
    float wp = w2p_o[(size_t)k * OUTC];
    float4 ht = *(const float4*)&s_h[0][k][0];
    float4 hp = *(const float4*)&s_h[1][k][0];
    acct[0] = fmaf(ht.x, wt, acct[0]);
    acct[1] = fmaf(ht.y, wt, acct[1]);
    acct[2] = fmaf(ht.z, wt, acct[2]);
    acct[3] = fmaf(ht.w, wt, acct[3]);
    accp[0] = fmaf(hp.x, wp, accp[0]);
    accp[1] = fmaf(hp.y, wp, accp[1]);
    accp[2] = fmaf(hp.z, wp, accp[2]);
    accp[3] = fmaf(hp.w, wp, accp[3]);
  }
  float bt = b2t[o], bp = b2p[o];
  const size_t posoff = (size_t)NB * NPOINT * OUTC;
#pragma unroll
  for (int rr = 0; rr < 4; ++rr) {
    size_t m = (size_t)(m0 + rr);
    out[m * OUTC + o] = acct[rr] + bt;
    out[posoff + m * OUTC + o] = accp[rr] + bp;
  }
}

extern "C" void kernel_launch(void* const* d_in, const int* in_sizes, int n_in,
                              void* d_out, int out_size, void* d_ws, size_t ws_size,
                              hipStream_t stream)
{
  const float* points = (const float*)d_in[0];
  const float* w1t = (const float*)d_in[1];
  const float* b1t = (const float*)d_in[2];
  const float* w2t = (const float*)d_in[3];
  const float* b2t = (const float*)d_in[4];
  const float* w1p = (const float*)d_in[5];
  const float* b1p = (const float*)d_in[6];
  const float* w2p = (const float*)d_in[7];
  const float* b2p = (const float*)d_in[8];
  float* out = (float*)d_out;

  char* ws = (char*)d_ws;
  unsigned long long* slots = (unsigned long long*)(ws + 0);  // 16*2*16*8 = 4096 B
  int* fps_idx = (int*)(ws + 4096);                           // 16*1024*4 = 65536 B

  hipLaunchKernelGGL(fps_init_kernel, dim3(2), dim3(256), 0, stream,
                     slots, fps_idx);

  void* args[3];
  args[0] = (void*)&points;
  args[1] = (void*)&slots;
  args[2] = (void*)&fps_idx;
  hipLaunchCooperativeKernel((void*)fps_kernel, dim3(128),
                             dim3(THREADS_FPS), args, 0, stream);

  hipLaunchKernelGGL(mlp_kernel, dim3(NB * NPOINT / 4), dim3(384), 0, stream,
                     points, fps_idx, w1t, b1t, w2t, b2t, w1p, b1p, w2p, b2p, out);
}